// Round 4
// baseline (233.532 us; speedup 1.0000x reference)
//
#include <hip/hip_runtime.h>
#include <hip/hip_bf16.h>
#include <stdint.h>

#define BB 256
#define TT 240
#define CC 512
#define KK 64
#define NCLS 4
#define CHUNK 32
#define NCHUNK 8   // 7 full chunks + 1 half (tvalid=16)

typedef __attribute__((ext_vector_type(8))) short bf16x8;
typedef __attribute__((ext_vector_type(4))) float f32x4;

__device__ __forceinline__ float u2f(unsigned int u) {
    union { unsigned int i; float f; } x; x.i = u; return x.f;
}
__device__ __forceinline__ float bf2f(unsigned short u) {
    return u2f(((unsigned int)u) << 16);
}
__device__ __forceinline__ unsigned short f2bf(float f) {
    union { float f; unsigned int i; } x; x.f = f;
    unsigned int r = x.i + 0x7FFFu + ((x.i >> 16) & 1u);  // RNE, finite inputs only
    return (unsigned short)(r >> 16);
}
__device__ __forceinline__ unsigned int pk2(float lo, float hi) {
    return ((unsigned int)f2bf(hi) << 16) | (unsigned int)f2bf(lo);
}

struct alignas(16) SMemChunk {
    unsigned short x[CHUNK][520];   // bf16 x chunk (converted from fp32), pad 512->520
    unsigned short xT[CC][40];      // transposed chunk, pad 32->40
    float logitsT[KK][33];          // logits^T then plain-a, pad 32->33
    unsigned short aT[KK][40];      // a' = a*rinv, bf16, pad 32->40
};
struct alignas(16) SMemEpi { unsigned short vbuf[KK * CC]; };  // 64 KB
union SMemU { SMemChunk c; SMemEpi e; };

__global__ __launch_bounds__(256, 1) void netvlad_kernel(
    const float* __restrict__ inp,    // [B,T,C] fp32
    const float* __restrict__ convw,  // [K,C]  fp32
    const float* __restrict__ cent,   // [K,C]  fp32
    const float* __restrict__ fcw,    // [NC, K*C] fp32
    const float* __restrict__ fcb,    // [NC] fp32
    float* __restrict__ out)          // [B,NC] fp32
{
    __shared__ SMemU sm;
    __shared__ float asum[KK];
    __shared__ float gred[16];
    __shared__ float fcred[4 * NCLS];
    __shared__ float vinv_sh;

    const int tid  = threadIdx.x;
    const int b    = blockIdx.x;
    const int w    = tid >> 6;     // wave 0..3
    const int lane = tid & 63;
    const int grp  = lane >> 4;    // 0..3
    const int col  = lane & 15;

    if (tid < KK) asum[tid] = 0.f;

    f32x4 acc[32];
    #pragma unroll
    for (int j = 0; j < 32; ++j) acc[j] = (f32x4){0.f, 0.f, 0.f, 0.f};

    // preconvert this lane's conv_w slice to bf16 registers (constant over chunks)
    bf16x8 cw[16];
    #pragma unroll
    for (int ks = 0; ks < 16; ++ks) {
        const float* p = convw + (size_t)(w * 16 + col) * CC + ks * 32 + grp * 8;
        float4 a0 = *(const float4*)p;
        float4 a1 = *(const float4*)(p + 4);
        bf16x8 v;
        v[0] = (short)f2bf(a0.x); v[1] = (short)f2bf(a0.y);
        v[2] = (short)f2bf(a0.z); v[3] = (short)f2bf(a0.w);
        v[4] = (short)f2bf(a1.x); v[5] = (short)f2bf(a1.y);
        v[6] = (short)f2bf(a1.z); v[7] = (short)f2bf(a1.w);
        cw[ks] = v;
    }

    const size_t ibase = (size_t)b * (TT * CC);

    // prefetch chunk 0: fp32 load -> packed bf16 regs
    uint4 pf[8];
    #pragma unroll
    for (int i = 0; i < 8; ++i) {
        int g = tid + i * 256;
        int t = g >> 6, c8 = (g & 63) << 3;
        const float* p = inp + ibase + (size_t)t * CC + c8;
        float4 u0 = *(const float4*)p;
        float4 u1 = *(const float4*)(p + 4);
        pf[i] = (uint4){pk2(u0.x, u0.y), pk2(u0.z, u0.w), pk2(u1.x, u1.y), pk2(u1.z, u1.w)};
    }

    for (int ch = 0; ch < NCHUNK; ++ch) {
        const int t0 = ch * CHUNK;
        const int tvalid = (TT - t0 < CHUNK) ? (TT - t0) : CHUNK;

        __syncthreads();  // previous chunk's LDS consumers done

        // stage prefetched chunk into LDS (bf16, row-major); zero-fill invalid tail rows
        #pragma unroll
        for (int i = 0; i < 8; ++i) {
            int g = tid + i * 256;
            int t = g >> 6, c8 = (g & 63) << 3;
            uint4 val = pf[i];
            if (t >= tvalid) val = (uint4){0u, 0u, 0u, 0u};
            *(uint4*)&sm.c.x[t][c8] = val;
        }
        // prefetch next chunk (fp32 -> bf16) — overlaps with this chunk's compute
        if (ch + 1 < NCHUNK) {
            int nt0 = t0 + CHUNK;
            #pragma unroll
            for (int i = 0; i < 8; ++i) {
                int g = tid + i * 256;
                int t = g >> 6, c8 = (g & 63) << 3;
                int gt = nt0 + t; if (gt > TT - 1) gt = TT - 1;  // clamp address only
                const float* p = inp + ibase + (size_t)gt * CC + c8;
                float4 u0 = *(const float4*)p;
                float4 u1 = *(const float4*)(p + 4);
                pf[i] = (uint4){pk2(u0.x, u0.y), pk2(u0.z, u0.w), pk2(u1.x, u1.y), pk2(u1.z, u1.w)};
            }
        }
        __syncthreads();  // x ready

        // LDS->LDS transpose x -> xT
        #pragma unroll
        for (int rep = 0; rep < 2; ++rep) {
            int c = tid + rep * 256;
            #pragma unroll
            for (int tb = 0; tb < 4; ++tb) {
                bf16x8 v;
                #pragma unroll
                for (int j = 0; j < 8; ++j) v[j] = (short)sm.c.x[tb * 8 + j][c];
                *(bf16x8*)&sm.c.xT[c][tb * 8] = v;
            }
        }

        // logits^T[cluster][t] (raw): wave w handles clusters 16w..16w+15
        {
            f32x4 lt0 = (f32x4){0,0,0,0}, lt1 = (f32x4){0,0,0,0};
            #pragma unroll
            for (int ks = 0; ks < 16; ++ks) {
                int c0 = ks * 32 + grp * 8;
                bf16x8 b0 = *(const bf16x8*)&sm.c.x[col][c0];
                bf16x8 b1 = *(const bf16x8*)&sm.c.x[16 + col][c0];
                lt0 = __builtin_amdgcn_mfma_f32_16x16x32_bf16(cw[ks], b0, lt0, 0, 0, 0);
                lt1 = __builtin_amdgcn_mfma_f32_16x16x32_bf16(cw[ks], b1, lt1, 0, 0, 0);
            }
            #pragma unroll
            for (int r = 0; r < 4; ++r) {
                int cl = w * 16 + grp * 4 + r;
                sm.c.logitsT[cl][col]      = lt0[r];
                sm.c.logitsT[cl][16 + col] = lt1[r];
            }
        }
        __syncthreads();  // logitsT + xT ready

        // softmax over clusters per t-column (8 threads / column); rinv inline
        {
            int t = tid >> 3, part = tid & 7;
            float ssp = 0.f;
            #pragma unroll
            for (int q = 0; q < 8; ++q) {
                const unsigned int* p = (const unsigned int*)&sm.c.x[t][part * 64 + q * 8];
                #pragma unroll
                for (int h = 0; h < 4; ++h) {
                    unsigned int u = p[h];
                    float lo = u2f(u << 16), hi = u2f(u & 0xFFFF0000u);
                    ssp += lo * lo + hi * hi;
                }
            }
            ssp += __shfl_xor(ssp, 1); ssp += __shfl_xor(ssp, 2); ssp += __shfl_xor(ssp, 4);
            float rinv = 1.f / fmaxf(sqrtf(ssp), 1e-12f);
            rinv = (t < tvalid) ? rinv : 0.f;   // mask invalid tail rows entirely

            float l[8]; float lmax = -1e30f;
            #pragma unroll
            for (int q = 0; q < 8; ++q) {
                l[q] = sm.c.logitsT[part * 8 + q][t] * rinv;
                lmax = fmaxf(lmax, l[q]);
            }
            lmax = fmaxf(lmax, __shfl_xor(lmax, 1));
            lmax = fmaxf(lmax, __shfl_xor(lmax, 2));
            lmax = fmaxf(lmax, __shfl_xor(lmax, 4));
            float es = 0.f;
            #pragma unroll
            for (int q = 0; q < 8; ++q) { l[q] = __expf(l[q] - lmax); es += l[q]; }
            es += __shfl_xor(es, 1); es += __shfl_xor(es, 2); es += __shfl_xor(es, 4);
            float is = 1.f / es;
            #pragma unroll
            for (int q = 0; q < 8; ++q) {
                float a = l[q] * is;
                sm.c.logitsT[part * 8 + q][t] = a;                   // plain a (for asum)
                sm.c.aT[part * 8 + q][t] = (unsigned short)f2bf(a * rinv);  // 0 for t>=tvalid
            }
        }
        __syncthreads();  // aT + plain-a ready

        // asum accumulation (wave 0) — plain a over valid t only
        if (tid < KK) {
            float s = 0.f;
            for (int t = 0; t < tvalid; ++t) s += sm.c.logitsT[tid][t];
            asum[tid] += s;
        }

        // VLAD MFMA: acc += a'^T @ x over this chunk's 32 timesteps
        {
            bf16x8 af = *(const bf16x8*)&sm.c.aT[w * 16 + col][grp * 8];
            #pragma unroll
            for (int j = 0; j < 32; ++j) {
                bf16x8 bf = *(const bf16x8*)&sm.c.xT[j * 16 + col][grp * 8];
                acc[j] = __builtin_amdgcn_mfma_f32_16x16x32_bf16(af, bf, acc[j], 0, 0, 0);
            }
        }
    }

    // ===== epilogue =====
    __syncthreads();

    // subtract asum*centroids (fp32), intra-normalize each cluster row
    float contrib = 0.f;
    #pragma unroll
    for (int r = 0; r < 4; ++r) {
        int cl = w * 16 + grp * 4 + r;
        float as = asum[cl];
        float ss = 0.f;
        #pragma unroll
        for (int j = 0; j < 32; ++j) {
            int c = j * 16 + col;
            float v = acc[j][r] - as * cent[(size_t)cl * CC + c];
            acc[j][r] = v;
            ss += v * v;
        }
        ss += __shfl_xor(ss, 1); ss += __shfl_xor(ss, 2);
        ss += __shfl_xor(ss, 4); ss += __shfl_xor(ss, 8);
        float inv = 1.f / fmaxf(sqrtf(ss), 1e-12f);
        #pragma unroll
        for (int j = 0; j < 32; ++j) {
            float v = acc[j][r] * inv;
            acc[j][r] = v;
            contrib += v * v;
        }
    }
    contrib += __shfl_xor(contrib, 1); contrib += __shfl_xor(contrib, 2);
    contrib += __shfl_xor(contrib, 4); contrib += __shfl_xor(contrib, 8);
    if (col == 0) gred[w * 4 + grp] = contrib;
    __syncthreads();
    if (tid == 0) {
        float tot = 0.f;
        #pragma unroll
        for (int i = 0; i < 16; ++i) tot += gred[i];
        vinv_sh = 1.f / fmaxf(sqrtf(tot), 1e-12f);
    }
    __syncthreads();

    // write normalized v to LDS (bf16) — aliases chunk-phase arrays (dead now)
    {
        float vinv = vinv_sh;
        #pragma unroll
        for (int r = 0; r < 4; ++r) {
            int cl = w * 16 + grp * 4 + r;
            #pragma unroll
            for (int j = 0; j < 32; ++j) {
                int c = j * 16 + col;
                sm.e.vbuf[cl * CC + c] = f2bf(acc[j][r] * vinv);
            }
        }
    }
    __syncthreads();

    // FC: NCLS dots of length 32768 (v bf16 from LDS, fcw fp32 from global)
    float pacc[NCLS] = {0.f, 0.f, 0.f, 0.f};
    #pragma unroll 4
    for (int i = 0; i < 16; ++i) {
        int idx = i * 2048 + tid * 8;
        bf16x8 vv = *(const bf16x8*)&sm.e.vbuf[idx];
        float vf[8];
        #pragma unroll
        for (int h = 0; h < 8; ++h) vf[h] = bf2f((unsigned short)vv[h]);
        #pragma unroll
        for (int nc = 0; nc < NCLS; ++nc) {
            const float* wp = fcw + (size_t)nc * (KK * CC) + idx;
            float4 w0 = *(const float4*)wp;
            float4 w1 = *(const float4*)(wp + 4);
            pacc[nc] += vf[0] * w0.x + vf[1] * w0.y + vf[2] * w0.z + vf[3] * w0.w
                      + vf[4] * w1.x + vf[5] * w1.y + vf[6] * w1.z + vf[7] * w1.w;
        }
    }
    #pragma unroll
    for (int nc = 0; nc < NCLS; ++nc) {
        #pragma unroll
        for (int m = 1; m < 64; m <<= 1) pacc[nc] += __shfl_xor(pacc[nc], m);
    }
    if (lane == 0) {
        #pragma unroll
        for (int nc = 0; nc < NCLS; ++nc) fcred[w * NCLS + nc] = pacc[nc];
    }
    __syncthreads();
    if (tid < NCLS) {
        float s = fcb[tid];
        #pragma unroll
        for (int ww = 0; ww < 4; ++ww) s += fcred[ww * NCLS + tid];
        float sg = 1.f / (1.f + __expf(-s));
        out[b * NCLS + tid] = sg;
    }
}

extern "C" void kernel_launch(void* const* d_in, const int* in_sizes, int n_in,
                              void* d_out, int out_size, void* d_ws, size_t ws_size,
                              hipStream_t stream) {
    const float* inp   = (const float*)d_in[0];
    const float* convw = (const float*)d_in[1];
    const float* cent  = (const float*)d_in[2];
    const float* fcw   = (const float*)d_in[3];
    const float* fcb   = (const float*)d_in[4];
    float* o = (float*)d_out;
    netvlad_kernel<<<BB, 256, 0, stream>>>(inp, convw, cent, fcw, fcb, o);
}

// Round 5
// 214.993 us; speedup vs baseline: 1.0862x; 1.0862x over previous
//
#include <hip/hip_runtime.h>
#include <hip/hip_bf16.h>
#include <stdint.h>

#define BB 256
#define TT 240
#define CC 512
#define KK 64
#define NCLS 4
#define CHUNK 32
#define NCHUNK 8   // 7 full chunks + 1 half (tvalid=16)
#define THREADS 512

typedef __attribute__((ext_vector_type(8))) short bf16x8;
typedef __attribute__((ext_vector_type(4))) float f32x4;

__device__ __forceinline__ float u2f(unsigned int u) {
    union { unsigned int i; float f; } x; x.i = u; return x.f;
}
__device__ __forceinline__ unsigned short f2bf(float f) {
    union { float f; unsigned int i; } x; x.f = f;
    unsigned int r = x.i + 0x7FFFu + ((x.i >> 16) & 1u);  // RNE, finite inputs only
    return (unsigned short)(r >> 16);
}
__device__ __forceinline__ unsigned int pk2(float lo, float hi) {
    return ((unsigned int)f2bf(hi) << 16) | (unsigned int)f2bf(lo);
}

struct alignas(16) SMemChunk {
    unsigned short x[CHUNK][520];   // bf16 x chunk, pad 512->520
    unsigned short xT[CC][40];      // transposed, pad 32->40
    float logitsA[CHUNK][65];       // t-major logits / plain-a, pad 64->65 (2-way banks)
    unsigned short aT[KK][40];      // a' = a*rinv bf16, pad 32->40
};
struct alignas(16) SMemEpi { unsigned short vbuf[KK * CC]; };  // 64 KB
union SMemU { SMemChunk c; SMemEpi e; };

__global__ __launch_bounds__(THREADS, 2) void netvlad_kernel(
    const float* __restrict__ inp,    // [B,T,C]
    const float* __restrict__ convw,  // [K,C]
    const float* __restrict__ cent,   // [K,C]
    const float* __restrict__ fcw,    // [NC, K*C]
    const float* __restrict__ fcb,    // [NC]
    float* __restrict__ out)          // [B,NC]
{
    __shared__ SMemU sm;
    __shared__ float asum[KK];
    __shared__ float ssred[2][KK];
    __shared__ float gred[8];
    __shared__ float fcred[8][NCLS];
    __shared__ float vinv_sh;

    const int tid  = threadIdx.x;
    const int b    = blockIdx.x;
    const int w    = tid >> 6;       // wave 0..7
    const int lane = tid & 63;
    const int grp  = (lane >> 4) & 3;
    const int col  = lane & 15;
    const int w2   = w >> 1;         // cluster group 0..3
    const int half = w & 1;          // t-half (logits) / c-half (VLAD)

    if (tid < KK) asum[tid] = 0.f;

    f32x4 acc[16];
    #pragma unroll
    for (int j = 0; j < 16; ++j) acc[j] = (f32x4){0.f, 0.f, 0.f, 0.f};

    // conv_w slice for this lane's cluster (w2*16+col), bf16 in regs
    bf16x8 cw[16];
    #pragma unroll
    for (int ks = 0; ks < 16; ++ks) {
        const float* p = convw + (size_t)(w2 * 16 + col) * CC + ks * 32 + grp * 8;
        float4 a0 = *(const float4*)p;
        float4 a1 = *(const float4*)(p + 4);
        bf16x8 v;
        v[0] = (short)f2bf(a0.x); v[1] = (short)f2bf(a0.y);
        v[2] = (short)f2bf(a0.z); v[3] = (short)f2bf(a0.w);
        v[4] = (short)f2bf(a1.x); v[5] = (short)f2bf(a1.y);
        v[6] = (short)f2bf(a1.z); v[7] = (short)f2bf(a1.w);
        cw[ks] = v;
    }

    const size_t ibase = (size_t)b * (TT * CC);

    // prefetch chunk 0 (fp32 -> packed bf16 regs)
    uint4 pf[4];
    #pragma unroll
    for (int i = 0; i < 4; ++i) {
        int g = tid + i * THREADS;
        int t = g >> 6, c8 = (g & 63) << 3;
        const float* p = inp + ibase + (size_t)t * CC + c8;
        float4 u0 = *(const float4*)p;
        float4 u1 = *(const float4*)(p + 4);
        pf[i] = (uint4){pk2(u0.x, u0.y), pk2(u0.z, u0.w), pk2(u1.x, u1.y), pk2(u1.z, u1.w)};
    }

    for (int ch = 0; ch < NCHUNK; ++ch) {
        const int t0 = ch * CHUNK;
        const int tvalid = (TT - t0 < CHUNK) ? (TT - t0) : CHUNK;

        __syncthreads();  // previous chunk's LDS consumers done

        // stage chunk into LDS; zero-fill invalid tail rows
        #pragma unroll
        for (int i = 0; i < 4; ++i) {
            int g = tid + i * THREADS;
            int t = g >> 6, c8 = (g & 63) << 3;
            uint4 val = pf[i];
            if (t >= tvalid) val = (uint4){0u, 0u, 0u, 0u};
            *(uint4*)&sm.c.x[t][c8] = val;
        }
        // prefetch next chunk
        if (ch + 1 < NCHUNK) {
            int nt0 = t0 + CHUNK;
            #pragma unroll
            for (int i = 0; i < 4; ++i) {
                int g = tid + i * THREADS;
                int t = g >> 6, c8 = (g & 63) << 3;
                int gt = nt0 + t; if (gt > TT - 1) gt = TT - 1;  // clamp address only
                const float* p = inp + ibase + (size_t)gt * CC + c8;
                float4 u0 = *(const float4*)p;
                float4 u1 = *(const float4*)(p + 4);
                pf[i] = (uint4){pk2(u0.x, u0.y), pk2(u0.z, u0.w), pk2(u1.x, u1.y), pk2(u1.z, u1.w)};
            }
        }
        __syncthreads();  // x ready

        // LDS transpose x -> xT: thread owns column c = tid
        {
            int c = tid;
            #pragma unroll
            for (int tb = 0; tb < 4; ++tb) {
                bf16x8 v;
                #pragma unroll
                for (int j = 0; j < 8; ++j) v[j] = (short)sm.c.x[tb * 8 + j][c];
                *(bf16x8*)&sm.c.xT[c][tb * 8] = v;
            }
        }

        // logits: wave (w2,half) -> clusters 16w2..+16, timesteps half*16..+16
        {
            f32x4 lt = (f32x4){0.f, 0.f, 0.f, 0.f};
            #pragma unroll
            for (int ks = 0; ks < 16; ++ks) {
                bf16x8 bb = *(const bf16x8*)&sm.c.x[half * 16 + col][ks * 32 + grp * 8];
                lt = __builtin_amdgcn_mfma_f32_16x16x32_bf16(cw[ks], bb, lt, 0, 0, 0);
            }
            #pragma unroll
            for (int r = 0; r < 4; ++r)
                sm.c.logitsA[half * 16 + col][w2 * 16 + grp * 4 + r] = lt[r];
        }
        __syncthreads();  // logitsA + xT ready

        // softmax per t-column: 16 threads/column, 4 clusters each
        {
            int t = tid >> 4, part = tid & 15;
            float ssp = 0.f;
            #pragma unroll
            for (int k = 0; k < 4; ++k) {
                uint4 u4 = *(const uint4*)&sm.c.x[t][part * 32 + k * 8];
                const unsigned int* pu = (const unsigned int*)&u4;
                #pragma unroll
                for (int h = 0; h < 4; ++h) {
                    unsigned int u = pu[h];
                    float lo = u2f(u << 16), hi = u2f(u & 0xFFFF0000u);
                    ssp += lo * lo + hi * hi;
                }
            }
            ssp += __shfl_xor(ssp, 1); ssp += __shfl_xor(ssp, 2);
            ssp += __shfl_xor(ssp, 4); ssp += __shfl_xor(ssp, 8);
            float rinv = 1.f / fmaxf(sqrtf(ssp), 1e-12f);
            rinv = (t < tvalid) ? rinv : 0.f;

            float l[4]; float lmax = -1e30f;
            #pragma unroll
            for (int q = 0; q < 4; ++q) {
                l[q] = sm.c.logitsA[t][q * 16 + part] * rinv;
                lmax = fmaxf(lmax, l[q]);
            }
            lmax = fmaxf(lmax, __shfl_xor(lmax, 1));
            lmax = fmaxf(lmax, __shfl_xor(lmax, 2));
            lmax = fmaxf(lmax, __shfl_xor(lmax, 4));
            lmax = fmaxf(lmax, __shfl_xor(lmax, 8));
            float es = 0.f;
            #pragma unroll
            for (int q = 0; q < 4; ++q) { l[q] = __expf(l[q] - lmax); es += l[q]; }
            es += __shfl_xor(es, 1); es += __shfl_xor(es, 2);
            es += __shfl_xor(es, 4); es += __shfl_xor(es, 8);
            float is = 1.f / es;
            #pragma unroll
            for (int q = 0; q < 4; ++q) {
                float a = l[q] * is;
                sm.c.logitsA[t][q * 16 + part] = a;                       // plain a (asum)
                sm.c.aT[q * 16 + part][t] = (unsigned short)f2bf(a * rinv);  // 0 for t>=tvalid
            }
        }
        __syncthreads();  // aT + plain-a ready

        // asum (64 threads) — plain a over valid t only
        if (tid < KK) {
            float s = 0.f;
            for (int t = 0; t < tvalid; ++t) s += sm.c.logitsA[t][tid];
            asum[tid] += s;
        }

        // VLAD: wave (w2,half) -> clusters 16w2..+16, c-range half*256..+256
        {
            bf16x8 af = *(const bf16x8*)&sm.c.aT[w2 * 16 + col][grp * 8];
            #pragma unroll
            for (int j = 0; j < 16; ++j) {
                bf16x8 bf = *(const bf16x8*)&sm.c.xT[half * 256 + j * 16 + col][grp * 8];
                acc[j] = __builtin_amdgcn_mfma_f32_16x16x32_bf16(af, bf, acc[j], 0, 0, 0);
            }
        }
    }

    // ===== epilogue =====
    __syncthreads();

    // centroid subtract + per-cluster partial sumsq (c-half per wave)
    #pragma unroll
    for (int r = 0; r < 4; ++r) {
        int cl = w2 * 16 + grp * 4 + r;
        float as = asum[cl];
        float ss = 0.f;
        #pragma unroll
        for (int j = 0; j < 16; ++j) {
            int c = half * 256 + j * 16 + col;
            float v = acc[j][r] - as * cent[(size_t)cl * CC + c];
            acc[j][r] = v;
            ss += v * v;
        }
        ss += __shfl_xor(ss, 1); ss += __shfl_xor(ss, 2);
        ss += __shfl_xor(ss, 4); ss += __shfl_xor(ss, 8);
        if (col == 0) ssred[half][cl] = ss;
    }
    __syncthreads();

    float contrib = 0.f;
    #pragma unroll
    for (int r = 0; r < 4; ++r) {
        int cl = w2 * 16 + grp * 4 + r;
        float ss = ssred[0][cl] + ssred[1][cl];
        float inv = 1.f / fmaxf(sqrtf(ss), 1e-12f);
        #pragma unroll
        for (int j = 0; j < 16; ++j) {
            float v = acc[j][r] * inv;
            acc[j][r] = v;
            contrib += v * v;
        }
    }
    #pragma unroll
    for (int m = 1; m < 64; m <<= 1) contrib += __shfl_xor(contrib, m);
    if (lane == 0) gred[w] = contrib;
    __syncthreads();
    if (tid == 0) {
        float tot = 0.f;
        #pragma unroll
        for (int i = 0; i < 8; ++i) tot += gred[i];
        vinv_sh = 1.f / fmaxf(sqrtf(tot), 1e-12f);
    }
    __syncthreads();

    // write normalized v (bf16) to LDS — chunk arrays dead now
    {
        float vinv = vinv_sh;
        #pragma unroll
        for (int r = 0; r < 4; ++r) {
            int cl = w2 * 16 + grp * 4 + r;
            #pragma unroll
            for (int j = 0; j < 16; ++j) {
                int c = half * 256 + j * 16 + col;
                sm.e.vbuf[cl * CC + c] = f2bf(acc[j][r] * vinv);
            }
        }
    }
    __syncthreads();

    // FC: NCLS dots of length 32768 (v bf16 LDS, fcw fp32 global)
    float pacc[NCLS] = {0.f, 0.f, 0.f, 0.f};
    #pragma unroll
    for (int i = 0; i < 8; ++i) {
        int idx = i * 4096 + tid * 8;
        bf16x8 vv = *(const bf16x8*)&sm.e.vbuf[idx];
        float vf[8];
        #pragma unroll
        for (int h = 0; h < 8; ++h) {
            union { unsigned int u; float f; } cvt;
            cvt.u = ((unsigned int)(unsigned short)vv[h]) << 16;
            vf[h] = cvt.f;
        }
        #pragma unroll
        for (int nc = 0; nc < NCLS; ++nc) {
            const float* wp = fcw + (size_t)nc * (KK * CC) + idx;
            float4 w0 = *(const float4*)wp;
            float4 w1 = *(const float4*)(wp + 4);
            pacc[nc] += vf[0] * w0.x + vf[1] * w0.y + vf[2] * w0.z + vf[3] * w0.w
                      + vf[4] * w1.x + vf[5] * w1.y + vf[6] * w1.z + vf[7] * w1.w;
        }
    }
    #pragma unroll
    for (int nc = 0; nc < NCLS; ++nc) {
        #pragma unroll
        for (int m = 1; m < 64; m <<= 1) pacc[nc] += __shfl_xor(pacc[nc], m);
    }
    if (lane == 0) {
        #pragma unroll
        for (int nc = 0; nc < NCLS; ++nc) fcred[w][nc] = pacc[nc];
    }
    __syncthreads();
    if (tid < NCLS) {
        float s = fcb[tid];
        #pragma unroll
        for (int ww = 0; ww < 8; ++ww) s += fcred[ww][tid];
        out[b * NCLS + tid] = 1.f / (1.f + __expf(-s));
    }
}

extern "C" void kernel_launch(void* const* d_in, const int* in_sizes, int n_in,
                              void* d_out, int out_size, void* d_ws, size_t ws_size,
                              hipStream_t stream) {
    const float* inp   = (const float*)d_in[0];
    const float* convw = (const float*)d_in[1];
    const float* cent  = (const float*)d_in[2];
    const float* fcw   = (const float*)d_in[3];
    const float* fcb   = (const float*)d_in[4];
    float* o = (float*)d_out;
    netvlad_kernel<<<BB, THREADS, 0, stream>>>(inp, convw, cent, fcw, fcb, o);
}

// Round 6
// 206.237 us; speedup vs baseline: 1.1324x; 1.0425x over previous
//
#include <hip/hip_runtime.h>
#include <hip/hip_bf16.h>
#include <stdint.h>

#define BB 256
#define TT 240
#define CC 512
#define KK 64
#define NCLS 4
#define CHUNK 32
#define NCHUNK 8   // 7 full chunks + 1 half (tvalid=16)
#define THREADS 512

typedef __attribute__((ext_vector_type(8))) short bf16x8;
typedef __attribute__((ext_vector_type(4))) float f32x4;

__device__ __forceinline__ unsigned short f2bf(float f) {
    union { float f; unsigned int i; } x; x.f = f;
    unsigned int r = x.i + 0x7FFFu + ((x.i >> 16) & 1u);  // RNE, finite inputs only
    return (unsigned short)(r >> 16);
}
__device__ __forceinline__ unsigned int pk2(float lo, float hi) {
    return ((unsigned int)f2bf(hi) << 16) | (unsigned int)f2bf(lo);
}
// LDS-only barrier: does NOT drain vmcnt, so global loads stay in flight
// across it (CK block_sync_lds pattern). All inter-wave deps here are LDS.
__device__ __forceinline__ void LB() {
    asm volatile("s_waitcnt lgkmcnt(0)\n\ts_barrier" ::: "memory");
}

struct alignas(16) SMemChunk {
    unsigned short x[CHUNK][520];   // bf16 x chunk, pad 512->520
    unsigned short xT[CC][40];      // transposed, pad 32->40
    float logitsA[CHUNK][65];       // t-major logits / plain-a, pad 64->65
    unsigned short aT[KK][40];      // a' = a*rinv bf16, pad 32->40
};
struct alignas(16) SMemEpi { unsigned short vbuf[KK * CC]; };  // 64 KB
union SMemU { SMemChunk c; SMemEpi e; };

__global__ __launch_bounds__(THREADS, 2) void netvlad_kernel(
    const float* __restrict__ inp,    // [B,T,C]
    const float* __restrict__ convw,  // [K,C]
    const float* __restrict__ cent,   // [K,C]
    const float* __restrict__ fcw,    // [NC, K*C]
    const float* __restrict__ fcb,    // [NC]
    float* __restrict__ out)          // [B,NC]
{
    __shared__ SMemU sm;
    __shared__ float sumsq_sh[CHUNK];
    __shared__ float asum[KK];
    __shared__ float ssred[2][KK];
    __shared__ float gred[8];
    __shared__ float fcred[8][NCLS];
    __shared__ float vinv_sh;

    const int tid  = threadIdx.x;
    const int b    = blockIdx.x;
    const int w    = tid >> 6;       // wave 0..7
    const int lane = tid & 63;
    const int grp  = (lane >> 4) & 3;
    const int col  = lane & 15;
    const int w2   = w >> 1;         // cluster group 0..3
    const int half = w & 1;          // t-half (logits) / c-half (VLAD)

    if (tid < KK) asum[tid] = 0.f;

    f32x4 acc[16];
    #pragma unroll
    for (int j = 0; j < 16; ++j) acc[j] = (f32x4){0.f, 0.f, 0.f, 0.f};

    // conv_w slice for this lane's cluster (w2*16+col), bf16 in regs
    bf16x8 cw[16];
    #pragma unroll
    for (int ks = 0; ks < 16; ++ks) {
        const float* p = convw + (size_t)(w2 * 16 + col) * CC + ks * 32 + grp * 8;
        float4 a0 = *(const float4*)p;
        float4 a1 = *(const float4*)(p + 4);
        bf16x8 v;
        v[0] = (short)f2bf(a0.x); v[1] = (short)f2bf(a0.y);
        v[2] = (short)f2bf(a0.z); v[3] = (short)f2bf(a0.w);
        v[4] = (short)f2bf(a1.x); v[5] = (short)f2bf(a1.y);
        v[6] = (short)f2bf(a1.z); v[7] = (short)f2bf(a1.w);
        cw[ks] = v;
    }

    const size_t ibase = (size_t)b * (TT * CC);

    // prefetch chunk 0 as RAW fp32 (no conversion here — keeps vmcnt wait away)
    float4 r0[4], r1[4];
    #pragma unroll
    for (int i = 0; i < 4; ++i) {
        int g = tid + i * THREADS;
        int t = g >> 6, c8 = (g & 63) << 3;
        const float* p = inp + ibase + (size_t)t * CC + c8;
        r0[i] = *(const float4*)p;
        r1[i] = *(const float4*)(p + 4);
    }

    for (int ch = 0; ch < NCHUNK; ++ch) {
        const int t0 = ch * CHUNK;
        const int tvalid = (TT - t0 < CHUNK) ? (TT - t0) : CHUNK;

        // ---- staging: convert raws -> bf16 LDS, per-row sumsq from fp32 ----
        // (no barrier needed before this: per-wave program order puts it after
        //  VLAD/asum of prev chunk; cross-wave x/aT readers finished >=1 barrier ago)
        #pragma unroll
        for (int i = 0; i < 4; ++i) {
            int g = tid + i * THREADS;
            int t = g >> 6, c8 = (g & 63) << 3;   // t is wave-uniform (= w + i*8)
            float4 u0 = r0[i], u1 = r1[i];
            uint4 val = (uint4){pk2(u0.x, u0.y), pk2(u0.z, u0.w),
                                pk2(u1.x, u1.y), pk2(u1.z, u1.w)};
            float s = u0.x*u0.x + u0.y*u0.y + u0.z*u0.z + u0.w*u0.w
                    + u1.x*u1.x + u1.y*u1.y + u1.z*u1.z + u1.w*u1.w;
            if (t >= tvalid) { val = (uint4){0u,0u,0u,0u}; s = 0.f; }
            *(uint4*)&sm.c.x[t][c8] = val;
            s += __shfl_xor(s, 1);  s += __shfl_xor(s, 2);  s += __shfl_xor(s, 4);
            s += __shfl_xor(s, 8);  s += __shfl_xor(s, 16); s += __shfl_xor(s, 32);
            if (lane == 0) sumsq_sh[t] = s;
        }
        // issue NEXT chunk's raw loads; consumed only at next staging (one full
        // chunk of compute away) — vmcnt latency hidden, LB() won't drain it.
        if (ch + 1 < NCHUNK) {
            int nt0 = t0 + CHUNK;
            #pragma unroll
            for (int i = 0; i < 4; ++i) {
                int g = tid + i * THREADS;
                int t = g >> 6, c8 = (g & 63) << 3;
                int gt = nt0 + t; if (gt > TT - 1) gt = TT - 1;  // clamp address only
                const float* p = inp + ibase + (size_t)gt * CC + c8;
                r0[i] = *(const float4*)p;
                r1[i] = *(const float4*)(p + 4);
            }
        }
        LB();  // x + sumsq ready

        // ---- LDS transpose x -> xT: thread owns column c = tid ----
        {
            int c = tid;
            #pragma unroll
            for (int tb = 0; tb < 4; ++tb) {
                bf16x8 v;
                #pragma unroll
                for (int j = 0; j < 8; ++j) v[j] = (short)sm.c.x[tb * 8 + j][c];
                *(bf16x8*)&sm.c.xT[c][tb * 8] = v;
            }
        }

        // ---- logits: wave (w2,half) -> clusters 16w2..+16, timesteps half*16..+16
        {
            f32x4 lt = (f32x4){0.f, 0.f, 0.f, 0.f};
            #pragma unroll
            for (int ks = 0; ks < 16; ++ks) {
                bf16x8 bb = *(const bf16x8*)&sm.c.x[half * 16 + col][ks * 32 + grp * 8];
                lt = __builtin_amdgcn_mfma_f32_16x16x32_bf16(cw[ks], bb, lt, 0, 0, 0);
            }
            #pragma unroll
            for (int r = 0; r < 4; ++r)
                sm.c.logitsA[half * 16 + col][w2 * 16 + grp * 4 + r] = lt[r];
        }
        LB();  // logitsA + xT ready

        // ---- softmax per t-column: 16 threads/column, 4 clusters each ----
        {
            int t = tid >> 4, part = tid & 15;
            float rinv = 1.f / fmaxf(sqrtf(sumsq_sh[t]), 1e-12f);
            rinv = (t < tvalid) ? rinv : 0.f;

            float l[4]; float lmax = -1e30f;
            #pragma unroll
            for (int q = 0; q < 4; ++q) {
                l[q] = sm.c.logitsA[t][q * 16 + part] * rinv;
                lmax = fmaxf(lmax, l[q]);
            }
            lmax = fmaxf(lmax, __shfl_xor(lmax, 1));
            lmax = fmaxf(lmax, __shfl_xor(lmax, 2));
            lmax = fmaxf(lmax, __shfl_xor(lmax, 4));
            lmax = fmaxf(lmax, __shfl_xor(lmax, 8));
            float es = 0.f;
            #pragma unroll
            for (int q = 0; q < 4; ++q) { l[q] = __expf(l[q] - lmax); es += l[q]; }
            es += __shfl_xor(es, 1); es += __shfl_xor(es, 2);
            es += __shfl_xor(es, 4); es += __shfl_xor(es, 8);
            float is = 1.f / es;
            #pragma unroll
            for (int q = 0; q < 4; ++q) {
                float a = l[q] * is;
                sm.c.logitsA[t][q * 16 + part] = a;                       // plain a
                sm.c.aT[q * 16 + part][t] = (unsigned short)f2bf(a * rinv);
            }
        }
        LB();  // aT + plain-a ready

        // ---- asum (64 threads; completes before next logits overwrite) ----
        if (tid < KK) {
            float s = 0.f;
            for (int t = 0; t < tvalid; ++t) s += sm.c.logitsA[t][tid];
            asum[tid] += s;
        }

        // ---- VLAD: wave (w2,half) -> clusters 16w2..+16, c-range half*256..+256
        {
            bf16x8 af = *(const bf16x8*)&sm.c.aT[w2 * 16 + col][grp * 8];
            #pragma unroll
            for (int j = 0; j < 16; ++j) {
                bf16x8 bf = *(const bf16x8*)&sm.c.xT[half * 256 + j * 16 + col][grp * 8];
                acc[j] = __builtin_amdgcn_mfma_f32_16x16x32_bf16(af, bf, acc[j], 0, 0, 0);
            }
        }
    }

    // ===== epilogue =====
    LB();

    // centroid subtract + per-cluster partial sumsq (c-half per wave)
    #pragma unroll
    for (int r = 0; r < 4; ++r) {
        int cl = w2 * 16 + grp * 4 + r;
        float as = asum[cl];
        float ss = 0.f;
        #pragma unroll
        for (int j = 0; j < 16; ++j) {
            int c = half * 256 + j * 16 + col;
            float v = acc[j][r] - as * cent[(size_t)cl * CC + c];
            acc[j][r] = v;
            ss += v * v;
        }
        ss += __shfl_xor(ss, 1); ss += __shfl_xor(ss, 2);
        ss += __shfl_xor(ss, 4); ss += __shfl_xor(ss, 8);
        if (col == 0) ssred[half][cl] = ss;
    }
    LB();

    float contrib = 0.f;
    #pragma unroll
    for (int r = 0; r < 4; ++r) {
        int cl = w2 * 16 + grp * 4 + r;
        float ss = ssred[0][cl] + ssred[1][cl];
        float inv = 1.f / fmaxf(sqrtf(ss), 1e-12f);
        #pragma unroll
        for (int j = 0; j < 16; ++j) {
            float v = acc[j][r] * inv;
            acc[j][r] = v;
            contrib += v * v;
        }
    }
    #pragma unroll
    for (int m = 1; m < 64; m <<= 1) contrib += __shfl_xor(contrib, m);
    if (lane == 0) gred[w] = contrib;
    LB();
    if (tid == 0) {
        float tot = 0.f;
        #pragma unroll
        for (int i = 0; i < 8; ++i) tot += gred[i];
        vinv_sh = 1.f / fmaxf(sqrtf(tot), 1e-12f);
    }
    LB();

    // write normalized v (bf16) to LDS — chunk arrays dead now
    {
        float vinv = vinv_sh;
        #pragma unroll
        for (int r = 0; r < 4; ++r) {
            int cl = w2 * 16 + grp * 4 + r;
            #pragma unroll
            for (int j = 0; j < 16; ++j) {
                int c = half * 256 + j * 16 + col;
                sm.e.vbuf[cl * CC + c] = f2bf(acc[j][r] * vinv);
            }
        }
    }
    LB();

    // FC: NCLS dots of length 32768 (v bf16 LDS, fcw fp32 global/L2)
    float pacc[NCLS] = {0.f, 0.f, 0.f, 0.f};
    #pragma unroll
    for (int i = 0; i < 8; ++i) {
        int idx = i * 4096 + tid * 8;
        bf16x8 vv = *(const bf16x8*)&sm.e.vbuf[idx];
        float vf[8];
        #pragma unroll
        for (int h = 0; h < 8; ++h) {
            union { unsigned int u; float f; } cvt;
            cvt.u = ((unsigned int)(unsigned short)vv[h]) << 16;
            vf[h] = cvt.f;
        }
        #pragma unroll
        for (int nc = 0; nc < NCLS; ++nc) {
            const float* wp = fcw + (size_t)nc * (KK * CC) + idx;
            float4 w0 = *(const float4*)wp;
            float4 w1 = *(const float4*)(wp + 4);
            pacc[nc] += vf[0] * w0.x + vf[1] * w0.y + vf[2] * w0.z + vf[3] * w0.w
                      + vf[4] * w1.x + vf[5] * w1.y + vf[6] * w1.z + vf[7] * w1.w;
        }
    }
    #pragma unroll
    for (int nc = 0; nc < NCLS; ++nc) {
        #pragma unroll
        for (int m = 1; m < 64; m <<= 1) pacc[nc] += __shfl_xor(pacc[nc], m);
    }
    if (lane == 0) {
        #pragma unroll
        for (int nc = 0; nc < NCLS; ++nc) fcred[w][nc] = pacc[nc];
    }
    LB();
    if (tid < NCLS) {
        float s = fcb[tid];
        #pragma unroll
        for (int ww = 0; ww < 8; ++ww) s += fcred[ww][tid];
        out[b * NCLS + tid] = 1.f / (1.f + __expf(-s));
    }
}

extern "C" void kernel_launch(void* const* d_in, const int* in_sizes, int n_in,
                              void* d_out, int out_size, void* d_ws, size_t ws_size,
                              hipStream_t stream) {
    const float* inp   = (const float*)d_in[0];
    const float* convw = (const float*)d_in[1];
    const float* cent  = (const float*)d_in[2];
    const float* fcw   = (const float*)d_in[3];
    const float* fcb   = (const float*)d_in[4];
    float* o = (float*)d_out;
    netvlad_kernel<<<BB, THREADS, 0, stream>>>(inp, convw, cent, fcw, fcb, o);
}

// Round 7
// 205.699 us; speedup vs baseline: 1.1353x; 1.0026x over previous
//
#include <hip/hip_runtime.h>
#include <hip/hip_bf16.h>
#include <stdint.h>

#define BB 256
#define TT 240
#define CC 512
#define KK 64
#define NCLS 4
#define CHUNK 32
#define NCHUNK 8   // 7 full chunks + 1 half (tvalid=16)
#define THREADS 1024

typedef __attribute__((ext_vector_type(8))) short bf16x8;
typedef __attribute__((ext_vector_type(4))) float f32x4;

__device__ __forceinline__ unsigned short f2bf(float f) {
    union { float f; unsigned int i; } x; x.f = f;
    unsigned int r = x.i + 0x7FFFu + ((x.i >> 16) & 1u);  // RNE, finite only
    return (unsigned short)(r >> 16);
}
// packed fp32x2 -> bf16x2 (v_cvt_pk_bf16_f32 on gfx950), lo in low half
__device__ __forceinline__ unsigned int pk2cvt(float lo, float hi) {
    union { __hip_bfloat162 h; unsigned int u; } c;
    c.h = __float22bfloat162_rn(float2{lo, hi});
    return c.u;
}
// LDS-only barrier: doesn't drain vmcnt (global prefetch stays in flight)
__device__ __forceinline__ void LB() {
    asm volatile("s_waitcnt lgkmcnt(0)\n\ts_barrier" ::: "memory");
}

struct alignas(16) SMemChunk {
    unsigned short x[CHUNK][520];   // bf16 x chunk, pad 512->520      (33.3 KB)
    unsigned short xT[CC][40];      // transposed, pad 32->40          (41.0 KB)
    float logitsP[2][CHUNK][68];    // k-half partial logits / plain-a (17.4 KB)
    unsigned short aT[KK][40];      // a' = a*rinv bf16                ( 5.1 KB)
};
struct alignas(16) SMemEpi { unsigned short vbuf[KK * CC]; };  // 64 KB
union SMemU { SMemChunk c; SMemEpi e; };

__global__ __launch_bounds__(THREADS, 4) void netvlad_kernel(
    const float* __restrict__ inp,    // [B,T,C]
    const float* __restrict__ convw,  // [K,C]
    const float* __restrict__ cent,   // [K,C]
    const float* __restrict__ fcw,    // [NC, K*C]
    const float* __restrict__ fcb,    // [NC]
    float* __restrict__ out)          // [B,NC]
{
    __shared__ SMemU sm;
    __shared__ float sumsq_sh[CHUNK];
    __shared__ float asum[KK];
    __shared__ float ssred[4][KK];
    __shared__ float gred[16];
    __shared__ float fcred[16][NCLS];
    __shared__ float vinv_sh;

    const int tid  = threadIdx.x;
    const int b    = blockIdx.x;
    const int w    = tid >> 6;       // wave 0..15
    const int lane = tid & 63;
    const int grp  = (lane >> 4) & 3;
    const int col  = lane & 15;
    const int cg   = w & 3;          // cluster group (logits/VLAD/epilogue)
    const int th   = (w >> 2) & 1;   // logits t-tile
    const int kh   = w >> 3;         // logits k-half
    const int cq   = w >> 2;         // VLAD c-quarter

    if (tid < KK) asum[tid] = 0.f;

    f32x4 acc[8];
    #pragma unroll
    for (int j = 0; j < 8; ++j) acc[j] = (f32x4){0.f, 0.f, 0.f, 0.f};

    // conv_w slice: clusters 16cg..+16, k-half kh (8 x bf16x8 = 16 VGPRs)
    bf16x8 cw[8];
    #pragma unroll
    for (int s = 0; s < 8; ++s) {
        const float* p = convw + (size_t)(cg * 16 + col) * CC + (kh * 8 + s) * 32 + grp * 8;
        float4 a0 = *(const float4*)p;
        float4 a1 = *(const float4*)(p + 4);
        bf16x8 v;
        v[0] = (short)f2bf(a0.x); v[1] = (short)f2bf(a0.y);
        v[2] = (short)f2bf(a0.z); v[3] = (short)f2bf(a0.w);
        v[4] = (short)f2bf(a1.x); v[5] = (short)f2bf(a1.y);
        v[6] = (short)f2bf(a1.z); v[7] = (short)f2bf(a1.w);
        cw[s] = v;
    }

    const size_t ibase = (size_t)b * (TT * CC);

    // prefetch chunk 0 raw fp32
    float4 r0[2], r1[2];
    #pragma unroll
    for (int i = 0; i < 2; ++i) {
        int g = tid + i * THREADS;
        int t = g >> 6, c8 = (g & 63) << 3;
        const float* p = inp + ibase + (size_t)t * CC + c8;
        r0[i] = *(const float4*)p;
        r1[i] = *(const float4*)(p + 4);
    }

    for (int ch = 0; ch < NCHUNK; ++ch) {
        const int t0 = ch * CHUNK;
        const int tvalid = (TT - t0 < CHUNK) ? (TT - t0) : CHUNK;

        // ---- phase A: stage regs -> bf16 LDS + row sumsq; issue next loads ----
        #pragma unroll
        for (int i = 0; i < 2; ++i) {
            int g = tid + i * THREADS;
            int t = g >> 6, c8 = (g & 63) << 3;   // t wave-uniform (= w + 16i)
            float4 u0 = r0[i], u1 = r1[i];
            uint4 val = (uint4){pk2cvt(u0.x, u0.y), pk2cvt(u0.z, u0.w),
                                pk2cvt(u1.x, u1.y), pk2cvt(u1.z, u1.w)};
            float s = u0.x*u0.x + u0.y*u0.y + u0.z*u0.z + u0.w*u0.w
                    + u1.x*u1.x + u1.y*u1.y + u1.z*u1.z + u1.w*u1.w;
            if (t >= tvalid) { val = (uint4){0u,0u,0u,0u}; s = 0.f; }
            *(uint4*)&sm.c.x[t][c8] = val;
            s += __shfl_xor(s, 1);  s += __shfl_xor(s, 2);  s += __shfl_xor(s, 4);
            s += __shfl_xor(s, 8);  s += __shfl_xor(s, 16); s += __shfl_xor(s, 32);
            if (lane == 0) sumsq_sh[t] = s;
        }
        if (ch + 1 < NCHUNK) {
            int nt0 = t0 + CHUNK;
            #pragma unroll
            for (int i = 0; i < 2; ++i) {
                int g = tid + i * THREADS;
                int t = g >> 6, c8 = (g & 63) << 3;
                int gt = nt0 + t; if (gt > TT - 1) gt = TT - 1;  // clamp address only
                const float* p = inp + ibase + (size_t)gt * CC + c8;
                r0[i] = *(const float4*)p;
                r1[i] = *(const float4*)(p + 4);
            }
        }
        LB();  // x + sumsq ready

        // ---- phase B: transpose (all 16 waves) + partial logits ----
        {
            int c = tid & 511, th2 = tid >> 9;
            #pragma unroll
            for (int tb2 = 0; tb2 < 2; ++tb2) {
                int tb = th2 * 2 + tb2;
                bf16x8 v;
                #pragma unroll
                for (int j = 0; j < 8; ++j) v[j] = (short)sm.c.x[tb * 8 + j][c];
                *(bf16x8*)&sm.c.xT[c][tb * 8] = v;
            }
        }
        {
            f32x4 lt = (f32x4){0.f, 0.f, 0.f, 0.f};
            #pragma unroll
            for (int s = 0; s < 8; ++s) {
                bf16x8 bb = *(const bf16x8*)&sm.c.x[th * 16 + col][(kh * 8 + s) * 32 + grp * 8];
                lt = __builtin_amdgcn_mfma_f32_16x16x32_bf16(cw[s], bb, lt, 0, 0, 0);
            }
            #pragma unroll
            for (int r = 0; r < 4; ++r)
                sm.c.logitsP[kh][th * 16 + col][cg * 16 + grp * 4 + r] = lt[r];
        }
        LB();  // xT + logitsP ready

        // ---- phase C: softmax per t (16 threads/col, threads 0..511) ----
        if (tid < 512) {
            int t = tid >> 4, part = tid & 15;
            float rinv = 1.f / fmaxf(sqrtf(sumsq_sh[t]), 1e-12f);
            rinv = (t < tvalid) ? rinv : 0.f;

            float l[4]; float lmax = -1e30f;
            #pragma unroll
            for (int q = 0; q < 4; ++q) {
                l[q] = (sm.c.logitsP[0][t][q * 16 + part] +
                        sm.c.logitsP[1][t][q * 16 + part]) * rinv;
                lmax = fmaxf(lmax, l[q]);
            }
            lmax = fmaxf(lmax, __shfl_xor(lmax, 1));
            lmax = fmaxf(lmax, __shfl_xor(lmax, 2));
            lmax = fmaxf(lmax, __shfl_xor(lmax, 4));
            lmax = fmaxf(lmax, __shfl_xor(lmax, 8));
            float es = 0.f;
            #pragma unroll
            for (int q = 0; q < 4; ++q) { l[q] = __expf(l[q] - lmax); es += l[q]; }
            es += __shfl_xor(es, 1); es += __shfl_xor(es, 2);
            es += __shfl_xor(es, 4); es += __shfl_xor(es, 8);
            float is = 1.f / es;
            #pragma unroll
            for (int q = 0; q < 4; ++q) {
                float a = l[q] * is;
                sm.c.logitsP[0][t][q * 16 + part] = a;                      // plain a
                sm.c.aT[q * 16 + part][t] = (unsigned short)f2bf(a * rinv); // 0 if masked
            }
        }
        LB();  // aT + plain-a ready

        // ---- phase D: asum + VLAD ----
        if (tid < KK) {
            float s = 0.f;
            for (int t = 0; t < tvalid; ++t) s += sm.c.logitsP[0][t][tid];
            asum[tid] += s;
        }
        {
            bf16x8 af = *(const bf16x8*)&sm.c.aT[cg * 16 + col][grp * 8];
            #pragma unroll
            for (int j = 0; j < 8; ++j) {
                bf16x8 bf = *(const bf16x8*)&sm.c.xT[cq * 128 + j * 16 + col][grp * 8];
                acc[j] = __builtin_amdgcn_mfma_f32_16x16x32_bf16(af, bf, acc[j], 0, 0, 0);
            }
        }
    }

    // ===== epilogue =====
    LB();

    // centroid subtract + per-cluster partial sumsq (c-quarter per wave)
    #pragma unroll
    for (int r = 0; r < 4; ++r) {
        int cl = cg * 16 + grp * 4 + r;
        float as = asum[cl];
        float ss = 0.f;
        #pragma unroll
        for (int j = 0; j < 8; ++j) {
            int c = cq * 128 + j * 16 + col;
            float v = acc[j][r] - as * cent[(size_t)cl * CC + c];
            acc[j][r] = v;
            ss += v * v;
        }
        ss += __shfl_xor(ss, 1); ss += __shfl_xor(ss, 2);
        ss += __shfl_xor(ss, 4); ss += __shfl_xor(ss, 8);
        if (col == 0) ssred[cq][cl] = ss;
    }
    LB();

    float contrib = 0.f;
    #pragma unroll
    for (int r = 0; r < 4; ++r) {
        int cl = cg * 16 + grp * 4 + r;
        float ss = ssred[0][cl] + ssred[1][cl] + ssred[2][cl] + ssred[3][cl];
        float inv = 1.f / fmaxf(sqrtf(ss), 1e-12f);
        #pragma unroll
        for (int j = 0; j < 8; ++j) {
            float v = acc[j][r] * inv;
            acc[j][r] = v;
            contrib += v * v;
        }
    }
    #pragma unroll
    for (int m = 1; m < 64; m <<= 1) contrib += __shfl_xor(contrib, m);
    if (lane == 0) gred[w] = contrib;
    LB();
    if (tid == 0) {
        float tot = 0.f;
        #pragma unroll
        for (int i = 0; i < 16; ++i) tot += gred[i];
        vinv_sh = 1.f / fmaxf(sqrtf(tot), 1e-12f);
    }
    LB();

    // write normalized v (bf16) to LDS — chunk arrays dead now
    {
        float vinv = vinv_sh;
        #pragma unroll
        for (int r = 0; r < 4; ++r) {
            int cl = cg * 16 + grp * 4 + r;
            #pragma unroll
            for (int j = 0; j < 8; ++j) {
                int c = cq * 128 + j * 16 + col;
                sm.e.vbuf[cl * CC + c] = f2bf(acc[j][r] * vinv);
            }
        }
    }
    LB();

    // FC: NCLS dots of length 32768
    float pacc[NCLS] = {0.f, 0.f, 0.f, 0.f};
    #pragma unroll
    for (int i = 0; i < 4; ++i) {
        int idx = i * 8192 + tid * 8;
        bf16x8 vv = *(const bf16x8*)&sm.e.vbuf[idx];
        float vf[8];
        #pragma unroll
        for (int h = 0; h < 8; ++h) {
            union { unsigned int u; float f; } cvt;
            cvt.u = ((unsigned int)(unsigned short)vv[h]) << 16;
            vf[h] = cvt.f;
        }
        #pragma unroll
        for (int nc = 0; nc < NCLS; ++nc) {
            const float* wp = fcw + (size_t)nc * (KK * CC) + idx;
            float4 w0 = *(const float4*)wp;
            float4 w1 = *(const float4*)(wp + 4);
            pacc[nc] += vf[0] * w0.x + vf[1] * w0.y + vf[2] * w0.z + vf[3] * w0.w
                      + vf[4] * w1.x + vf[5] * w1.y + vf[6] * w1.z + vf[7] * w1.w;
        }
    }
    #pragma unroll
    for (int nc = 0; nc < NCLS; ++nc) {
        #pragma unroll
        for (int m = 1; m < 64; m <<= 1) pacc[nc] += __shfl_xor(pacc[nc], m);
    }
    if (lane == 0) {
        #pragma unroll
        for (int nc = 0; nc < NCLS; ++nc) fcred[w][nc] = pacc[nc];
    }
    LB();
    if (tid < NCLS) {
        float s = fcb[tid];
        #pragma unroll
        for (int ww = 0; ww < 16; ++ww) s += fcred[ww][tid];
        out[b * NCLS + tid] = 1.f / (1.f + __expf(-s));
    }
}

extern "C" void kernel_launch(void* const* d_in, const int* in_sizes, int n_in,
                              void* d_out, int out_size, void* d_ws, size_t ws_size,
                              hipStream_t stream) {
    const float* inp   = (const float*)d_in[0];
    const float* convw = (const float*)d_in[1];
    const float* cent  = (const float*)d_in[2];
    const float* fcw   = (const float*)d_in[3];
    const float* fcb   = (const float*)d_in[4];
    float* o = (float*)d_out;
    netvlad_kernel<<<BB, THREADS, 0, stream>>>(inp, convw, cent, fcw, fcb, o);
}